// Round 1
// baseline (781.962 us; speedup 1.0000x reference)
//
#include <hip/hip_runtime.h>
#include <hip/hip_bf16.h>

#define NN 100000
#define DD 128
#define RR 8
#define EE 100000

typedef __attribute__((ext_vector_type(8))) short short8;
typedef __attribute__((ext_vector_type(4))) float f32x4;

__device__ __forceinline__ unsigned short f2bf(float v) {
  union { float f; unsigned int u; } x; x.f = v;
  unsigned int r = (x.u + 0x7FFFu + ((x.u >> 16) & 1u)) >> 16;
  return (unsigned short)r;
}

// ---- cast f32 -> bf16, 4 elems/thread, grid-stride
__global__ void k_cast4(const float* __restrict__ src, unsigned short* __restrict__ dst, int n4) {
  int i = blockIdx.x * blockDim.x + threadIdx.x;
  int stride = gridDim.x * blockDim.x;
  for (; i < n4; i += stride) {
    float4 v = reinterpret_cast<const float4*>(src)[i];
    ushort4 o;
    o.x = f2bf(v.x); o.y = f2bf(v.y); o.z = f2bf(v.z); o.w = f2bf(v.w);
    reinterpret_cast<ushort4*>(dst)[i] = o;
  }
}

// ---- cast + transpose weights: src[r][k][o] f32 -> dst[r][o][k] bf16
__global__ void k_castT(const float* __restrict__ src, unsigned short* __restrict__ dst, int total) {
  int i = blockIdx.x * blockDim.x + threadIdx.x;
  if (i >= total) return;
  int r = i >> 14;
  int k = (i >> 7) & 127;
  int o = i & 127;
  dst[(r << 14) + (o << 7) + k] = f2bf(src[i]);
}

__global__ void k_zero(unsigned int* __restrict__ p, int n) {
  int i = blockIdx.x * blockDim.x + threadIdx.x;
  if (i < n) p[i] = 0u;
}

// ---- mask[r][n] = 1 if n is a target of relation r
__global__ void k_mask(const int* __restrict__ edge_index, unsigned char* __restrict__ mask) {
  int e = blockIdx.x * blockDim.x + threadIdx.x;
  int r = blockIdx.y;
  if (e >= EE) return;
  int tgt = edge_index[(size_t)r * 2 * EE + EE + e];
  mask[(size_t)r * NN + tgt] = 1;
}

// ================= GEMM kernels =================
// LDS tiles 128x128 bf16, chunk-XOR swizzle: chunk kc (8 bf16 = 16B) of row R
// stored at element (R<<7) + ((kc ^ (R&7))<<3). Keeps ds_*_b128 bank-uniform.

__device__ __forceinline__ void stage_B(const unsigned short* __restrict__ Wt,
                                        unsigned short* __restrict__ lB, int t) {
#pragma unroll
  for (int c = 0; c < 8; ++c) {
    int g = t + 256 * c;
    int o = g >> 4, kc = g & 15;
    int4 v = *reinterpret_cast<const int4*>(Wt + (o << 7) + (kc << 3));
    *reinterpret_cast<int4*>(&lB[(o << 7) + ((kc ^ (o & 7)) << 3)]) = v;
  }
}

__device__ __forceinline__ void stage_A_row(const unsigned short* __restrict__ gp,
                                            unsigned short* __restrict__ lA,
                                            int lr, int half) {
#pragma unroll
  for (int c = 0; c < 8; ++c) {
    int kc = half * 8 + c;
    int4 v = *reinterpret_cast<const int4*>(gp + (kc << 3));
    *reinterpret_cast<int4*>(&lA[(lr << 7) + ((kc ^ (lr & 7)) << 3)]) = v;
  }
}

#define MFMA_BODY                                                                     \
  const int w = t >> 6, l = t & 63;                                                   \
  const int lrow = l & 15, kgrp = l >> 4;                                             \
  f32x4 acc[2][8] = {};                                                               \
  _Pragma("unroll")                                                                   \
  for (int ks = 0; ks < 4; ++ks) {                                                    \
    int kc = ks * 4 + kgrp;                                                           \
    int ra = w * 32 + lrow;                                                           \
    int rb = ra + 16;                                                                 \
    short8 a0 = *reinterpret_cast<const short8*>(&lA[(ra << 7) + ((kc ^ (ra & 7)) << 3)]); \
    short8 a1 = *reinterpret_cast<const short8*>(&lA[(rb << 7) + ((kc ^ (rb & 7)) << 3)]); \
    _Pragma("unroll")                                                                 \
    for (int ct = 0; ct < 8; ++ct) {                                                  \
      int ro = ct * 16 + lrow;                                                        \
      short8 b = *reinterpret_cast<const short8*>(&lB[(ro << 7) + ((kc ^ (ro & 7)) << 3)]); \
      acc[0][ct] = __builtin_amdgcn_mfma_f32_16x16x32_bf16(a0, b, acc[0][ct], 0, 0, 0);    \
      acc[1][ct] = __builtin_amdgcn_mfma_f32_16x16x32_bf16(a1, b, acc[1][ct], 0, 0, 0);    \
    }                                                                                 \
  }

// out[row,:] = Xb[row,:] @ W  (W given pre-transposed [o][k]); non-atomic init write
__launch_bounds__(256, 2)
__global__ void k_gemm_self(const unsigned short* __restrict__ Xb,
                            const unsigned short* __restrict__ Wt,
                            float* __restrict__ out) {
  __shared__ __align__(16) unsigned short lA[128 * 128];
  __shared__ __align__(16) unsigned short lB[128 * 128];
  const int t = threadIdx.x;
  const int row0 = blockIdx.x * 128;

  stage_B(Wt, lB, t);
  {
    int lr = t >> 1, half = t & 1;
    int grow = row0 + lr;
    int sr = grow < NN ? grow : 0;
    stage_A_row(Xb + (size_t)sr * 128, lA, lr, half);
  }
  __syncthreads();

  MFMA_BODY

#pragma unroll
  for (int rt = 0; rt < 2; ++rt) {
#pragma unroll
    for (int j = 0; j < 4; ++j) {
      int grow = row0 + w * 32 + rt * 16 + kgrp * 4 + j;
      if (grow < NN) {
        float* op = out + (size_t)grow * 128 + lrow;
#pragma unroll
        for (int ct = 0; ct < 8; ++ct) op[ct * 16] = acc[rt][ct][j];
      }
    }
  }
}

// per-edge: agg[tgt[e],:] += w[e] * (Xb[src[e],:] @ relW[r]); atomic scatter
__launch_bounds__(256, 2)
__global__ void k_gemm_edge(const unsigned short* __restrict__ Xb,
                            const unsigned short* __restrict__ Wt_all,
                            const int* __restrict__ edge_index,
                            const float* __restrict__ ew,
                            float* __restrict__ agg) {
  __shared__ __align__(16) unsigned short lA[128 * 128];
  __shared__ __align__(16) unsigned short lB[128 * 128];
  const int t = threadIdx.x;
  const int r = blockIdx.y;
  const int e0 = blockIdx.x * 128;
  const int* src_p = edge_index + (size_t)r * 2 * EE;
  const int* tgt_p = src_p + EE;
  const float* w_p = ew + (size_t)r * EE;

  stage_B(Wt_all + (r << 14), lB, t);
  {
    int lr = t >> 1, half = t & 1;
    int e = e0 + lr;
    int s = (e < EE) ? src_p[e] : 0;
    stage_A_row(Xb + (size_t)s * 128, lA, lr, half);
  }
  __syncthreads();

  MFMA_BODY

#pragma unroll
  for (int rt = 0; rt < 2; ++rt) {
#pragma unroll
    for (int j = 0; j < 4; ++j) {
      int lr2 = w * 32 + rt * 16 + kgrp * 4 + j;
      int e2 = e0 + lr2;
      if (e2 < EE) {
        float wgt = w_p[e2];
        int tg = tgt_p[e2];
        float* op = agg + (size_t)tg * 128 + lrow;
#pragma unroll
        for (int ct = 0; ct < 8; ++ct)
          unsafeAtomicAdd(&op[ct * 16], wgt * acc[rt][ct][j]);
      }
    }
  }
}

// epilogue layer1: h_bf16 = bf16(relu(h32 + sum_r mask[r][n]*bias[r,:]))
__global__ void k_epi1(const float* __restrict__ h32, const unsigned char* __restrict__ mask,
                       const float* __restrict__ bias, unsigned short* __restrict__ hb) {
  int gid = blockIdx.x * blockDim.x + threadIdx.x;
  if (gid >= NN * 32) return;
  int n = gid >> 5, c = (gid & 31) << 2;
  float4 v = *reinterpret_cast<const float4*>(h32 + (size_t)n * 128 + c);
  float b0 = 0, b1 = 0, b2 = 0, b3 = 0;
#pragma unroll
  for (int r = 0; r < RR; ++r) {
    if (mask[(size_t)r * NN + n]) {
      const float* bp = bias + r * 128 + c;
      b0 += bp[0]; b1 += bp[1]; b2 += bp[2]; b3 += bp[3];
    }
  }
  ushort4 o;
  o.x = f2bf(fmaxf(v.x + b0, 0.f));
  o.y = f2bf(fmaxf(v.y + b1, 0.f));
  o.z = f2bf(fmaxf(v.z + b2, 0.f));
  o.w = f2bf(fmaxf(v.w + b3, 0.f));
  *reinterpret_cast<ushort4*>(hb + (size_t)n * 128 + c) = o;
}

// epilogue layer2: out += sum_r mask[r][n]*bias[r,:]  (in-place f32)
__global__ void k_epi2(float* __restrict__ out, const unsigned char* __restrict__ mask,
                       const float* __restrict__ bias) {
  int gid = blockIdx.x * blockDim.x + threadIdx.x;
  if (gid >= NN * 32) return;
  int n = gid >> 5, c = (gid & 31) << 2;
  float b0 = 0, b1 = 0, b2 = 0, b3 = 0;
  bool any = false;
#pragma unroll
  for (int r = 0; r < RR; ++r) {
    if (mask[(size_t)r * NN + n]) {
      any = true;
      const float* bp = bias + r * 128 + c;
      b0 += bp[0]; b1 += bp[1]; b2 += bp[2]; b3 += bp[3];
    }
  }
  if (any) {
    float* p = out + (size_t)n * 128 + c;
    float4 v = *reinterpret_cast<const float4*>(p);
    v.x += b0; v.y += b1; v.z += b2; v.w += b3;
    *reinterpret_cast<float4*>(p) = v;
  }
}

extern "C" void kernel_launch(void* const* d_in, const int* in_sizes, int n_in,
                              void* d_out, int out_size, void* d_ws, size_t ws_size,
                              hipStream_t stream) {
  const float* X   = (const float*)d_in[0];
  const int*   EI  = (const int*)d_in[1];
  const float* EW  = (const float*)d_in[2];
  const float* rW1 = (const float*)d_in[3];
  const float* sW1 = (const float*)d_in[4];
  const float* b1  = (const float*)d_in[5];
  const float* rW2 = (const float*)d_in[6];
  const float* sW2 = (const float*)d_in[7];
  const float* b2  = (const float*)d_in[8];
  float* out = (float*)d_out;
  char* ws = (char*)d_ws;

  size_t off = 0;
  auto take = [&](size_t sz) { char* p = ws + off; off += (sz + 255) & ~(size_t)255; return p; };
  unsigned short* Xb   = (unsigned short*)take((size_t)NN * DD * 2);
  unsigned short* hb   = (unsigned short*)take((size_t)NN * DD * 2);
  float*          h32  = (float*)take((size_t)NN * DD * 4);
  unsigned char*  mask = (unsigned char*)take((size_t)RR * NN);
  unsigned short* rW1t = (unsigned short*)take((size_t)RR * DD * DD * 2);
  unsigned short* sW1t = (unsigned short*)take((size_t)DD * DD * 2);
  unsigned short* rW2t = (unsigned short*)take((size_t)RR * DD * DD * 2);
  unsigned short* sW2t = (unsigned short*)take((size_t)DD * DD * 2);

  // casts
  k_cast4<<<2048, 256, 0, stream>>>(X, Xb, NN * DD / 4);
  k_castT<<<(RR * DD * DD + 255) / 256, 256, 0, stream>>>(rW1, rW1t, RR * DD * DD);
  k_castT<<<(DD * DD + 255) / 256, 256, 0, stream>>>(sW1, sW1t, DD * DD);
  k_castT<<<(RR * DD * DD + 255) / 256, 256, 0, stream>>>(rW2, rW2t, RR * DD * DD);
  k_castT<<<(DD * DD + 255) / 256, 256, 0, stream>>>(sW2, sW2t, DD * DD);

  // target mask (shared by both layers)
  k_zero<<<(RR * NN / 4 + 255) / 256, 256, 0, stream>>>((unsigned int*)mask, RR * NN / 4);
  k_mask<<<dim3((EE + 255) / 256, RR), 256, 0, stream>>>(EI, mask);

  const int nblk = (NN + 127) / 128;  // 782
  // ---- layer 1
  k_gemm_self<<<nblk, 256, 0, stream>>>(Xb, sW1t, h32);
  k_gemm_edge<<<dim3(nblk, RR), 256, 0, stream>>>(Xb, rW1t, EI, EW, h32);
  k_epi1<<<(NN * 32 + 255) / 256, 256, 0, stream>>>(h32, mask, b1, hb);
  // ---- layer 2
  k_gemm_self<<<nblk, 256, 0, stream>>>(hb, sW2t, out);
  k_gemm_edge<<<dim3(nblk, RR), 256, 0, stream>>>(hb, rW2t, EI, EW, out);
  k_epi2<<<(NN * 32 + 255) / 256, 256, 0, stream>>>(out, mask, b2);
}